// Round 1
// baseline (161.124 us; speedup 1.0000x reference)
//
#include <hip/hip_runtime.h>
#include <hip/hip_bf16.h>
#include <stdint.h>
#include <math.h>

// ---------- types ----------
typedef __bf16 bf16;
typedef bf16  bf16x4  __attribute__((ext_vector_type(4)));
typedef bf16  bf16x8  __attribute__((ext_vector_type(8)));
typedef float floatx4 __attribute__((ext_vector_type(4)));

#define MFMA_16x16x32_BF16(a, b, c) \
  __builtin_amdgcn_mfma_f32_16x16x32_bf16((a), (b), (c), 0, 0, 0)

__device__ __forceinline__ int imin(int a, int b) { return a < b ? a : b; }
__device__ __forceinline__ int imax(int a, int b) { return a > b ? a : b; }

// async global->LDS, 16B per lane. LDS dest must be wave-uniform base + lane*16.
__device__ __forceinline__ void load_lds16(const void* g, void* l) {
  __builtin_amdgcn_global_load_lds(
      (const __attribute__((address_space(1))) unsigned int*)g,
      (__attribute__((address_space(3))) unsigned int*)l, 16, 0, 0);
}

// ---------- constants ----------
// B=2, L=2048, D=1024, H=16, dh=64, WINDOW=256
#define LSEQ 2048
#define DMODEL 1024
#define NH 16
#define DH 64

// ============================================================
// 1) hidden fp32 -> bf16 (same layout, [4096,1024])
// ============================================================
__global__ void pack_hidden(const float4* __restrict__ x, uint16_t* __restrict__ y) {
  int i = blockIdx.x * 256 + threadIdx.x;   // grid covers exactly 4096*1024/4
  float4 f = x[i];
  bf16x4 v;
  v[0] = (bf16)f.x; v[1] = (bf16)f.y; v[2] = (bf16)f.z; v[3] = (bf16)f.w;
  *(bf16x4*)&y[(size_t)i * 4] = v;          // 8B store
}

// ============================================================
// 2) W [k][n] fp32 -> Wt [n][k] bf16, 32x32 LDS tile transpose, z = q/k/v
// ============================================================
__global__ void pack_w(const float* __restrict__ Wq, const float* __restrict__ Wk,
                       const float* __restrict__ Wv, uint16_t* __restrict__ Wt) {
  __shared__ float tile[32][33];
  const int z = blockIdx.z;
  const float* W = (z == 0) ? Wq : (z == 1) ? Wk : Wv;
  const int k0 = blockIdx.y * 32, n0 = blockIdx.x * 32;
  const int tx = threadIdx.x, ty = threadIdx.y;  // block (32,8)
#pragma unroll
  for (int i = 0; i < 4; ++i)
    tile[ty + i * 8][tx] = W[(size_t)(k0 + ty + i * 8) * DMODEL + n0 + tx];
  __syncthreads();
  uint16_t* out = Wt + (size_t)z * DMODEL * DMODEL;
#pragma unroll
  for (int i = 0; i < 4; ++i)
    *(bf16*)&out[(size_t)(n0 + ty + i * 8) * DMODEL + k0 + tx] =
        (bf16)tile[tx][ty + i * 8];
}

// ============================================================
// 3) QKV GEMM: C[m][n] = A[m][:] . W[:][n] + bias[n]
//    A: hidden bf16 [4096,1024] (k-innermost), Bt: Wt [n][k] (k-innermost)
//    128x128 tile, BK=32, 4 waves (2x2 of 64x64), 16x16x32 MFMA.
//    z=0 -> q [B,H,L,dh]; z=1 -> k same; z=2 -> v TRANSPOSED [B,H,dh,L].
// ============================================================
__global__ __launch_bounds__(256, 2) void qkv_gemm(
    const uint16_t* __restrict__ A, const uint16_t* __restrict__ Wt,
    const float* __restrict__ bq, const float* __restrict__ bk,
    const float* __restrict__ bv,
    uint16_t* __restrict__ outq, uint16_t* __restrict__ outk,
    uint16_t* __restrict__ outvt) {
  __shared__ __attribute__((aligned(16))) uint16_t lds[8192];  // A:4096, B:4096
  const int z = blockIdx.z;
  const int m0 = blockIdx.y * 128;
  const int n0 = blockIdx.x * 128;
  const uint16_t* Bt = Wt + (size_t)z * DMODEL * DMODEL;
  const float* bias = (z == 0) ? bq : (z == 1) ? bk : bv;

  const int t = threadIdx.x;
  const int lane = t & 63;
  const int wave = t >> 6;
  const int wm = (wave >> 1) * 64;
  const int wn = (wave & 1) * 64;
  const int col = lane & 15;
  const int quad = lane >> 4;

  floatx4 acc[4][4] = {};

  for (int kk = 0; kk < 32; ++kk) {
    const int k0 = kk * 32;
    // stage A-tile (128x32) + B-tile (128x32): 1024 chunks of 16B, 4/thread.
    // XOR swizzle on the 4 16B-chunks of each row to spread b128-read banks.
#pragma unroll
    for (int c = 0; c < 4; ++c) {
      int chunk = t + c * 256;
      int cc = chunk & 511;
      int row = cc >> 2;
      int col16 = (cc & 3) ^ (row & 3);
      const uint16_t* g = (chunk < 512)
          ? A  + (size_t)(m0 + row) * DMODEL + k0 + col16 * 8
          : Bt + (size_t)(n0 + row) * DMODEL + k0 + col16 * 8;
      load_lds16(g, &lds[chunk * 8]);
    }
    __syncthreads();

    bf16x8 afrag[4], bfrag[4];
#pragma unroll
    for (int mi = 0; mi < 4; ++mi) {
      int r = wm + mi * 16 + col;
      afrag[mi] = *(const bf16x8*)&lds[r * 32 + ((quad ^ (r & 3)) * 8)];
    }
#pragma unroll
    for (int nj = 0; nj < 4; ++nj) {
      int r = wn + nj * 16 + col;
      bfrag[nj] = *(const bf16x8*)&lds[4096 + r * 32 + ((quad ^ (r & 3)) * 8)];
    }
#pragma unroll
    for (int mi = 0; mi < 4; ++mi)
#pragma unroll
      for (int nj = 0; nj < 4; ++nj)
        acc[mi][nj] = MFMA_16x16x32_BF16(afrag[mi], bfrag[nj], acc[mi][nj]);
    __syncthreads();
  }

  // epilogue: C/D layout col=lane&15, row=quad*4+reg
#pragma unroll
  for (int nj = 0; nj < 4; ++nj) {
    int gn = n0 + wn + nj * 16 + col;
    float bb = bias[gn];
    int h = gn >> 6, d = gn & 63;
#pragma unroll
    for (int mi = 0; mi < 4; ++mi) {
#pragma unroll
      for (int r = 0; r < 4; ++r) {
        int gm = m0 + wm + mi * 16 + quad * 4 + r;
        int b = gm >> 11, l = gm & 2047;
        bf16 hv = (bf16)(acc[mi][nj][r] + bb);
        if (z == 0)
          *(bf16*)&outq[(((size_t)b * NH + h) * LSEQ + l) * DH + d] = hv;
        else if (z == 1)
          *(bf16*)&outk[(((size_t)b * NH + h) * LSEQ + l) * DH + d] = hv;
        else
          *(bf16*)&outvt[(((size_t)b * NH + h) * DH + d) * LSEQ + l] = hv;
      }
    }
  }
}

// ============================================================
// 4) windowed attention, flash-style. 1 wave = 16 queries of one (b,h).
//    keys [q0-256, q0+32) in 9 chunks of 32, masked; online softmax.
// ============================================================
__global__ __launch_bounds__(256, 2) void attn(
    const uint16_t* __restrict__ Q, const uint16_t* __restrict__ K,
    const uint16_t* __restrict__ Vt, float* __restrict__ out) {
  __shared__ __attribute__((aligned(16))) uint16_t plds[4][16 * 40];  // P, stride 40
  const int t = threadIdx.x;
  const int lane = t & 63;
  const int w = t >> 6;
  const int task = blockIdx.x * 4 + w;   // 0..4095
  const int bh = task >> 7;              // 0..31
  const int q0 = (task & 127) * 16;
  const int b = bh >> 4, h = bh & 15;
  const uint16_t* Qp = Q + (size_t)bh * LSEQ * DH;
  const uint16_t* Kp = K + (size_t)bh * LSEQ * DH;
  const uint16_t* Vp = Vt + (size_t)bh * DH * LSEQ;
  const int col = lane & 15, quad = lane >> 4;

  // Q A-frags: lane holds Q[q0+col][quad*8+j], two 32-wide k chunks
  bf16x8 qf0 = *(const bf16x8*)&Qp[(size_t)(q0 + col) * DH + quad * 8];
  bf16x8 qf1 = *(const bf16x8*)&Qp[(size_t)(q0 + col) * DH + 32 + quad * 8];

  floatx4 o[4] = {};        // 16q x 64d accumulator (C layout)
  float mrow[4], lrow[4];
#pragma unroll
  for (int r = 0; r < 4; ++r) { mrow[r] = -INFINITY; lrow[r] = 0.0f; }

  for (int c = 0; c < 9; ++c) {
    const int kc = q0 - 256 + c * 32;
    floatx4 s0 = {0.f, 0.f, 0.f, 0.f}, s1 = {0.f, 0.f, 0.f, 0.f};
    {
      int krc = imin(imax(kc + col, 0), LSEQ - 1);
      bf16x8 kf0 = *(const bf16x8*)&Kp[(size_t)krc * DH + quad * 8];
      bf16x8 kf1 = *(const bf16x8*)&Kp[(size_t)krc * DH + 32 + quad * 8];
      s0 = MFMA_16x16x32_BF16(qf0, kf0, s0);
      s0 = MFMA_16x16x32_BF16(qf1, kf1, s0);
    }
    {
      int krc = imin(imax(kc + 16 + col, 0), LSEQ - 1);
      bf16x8 kf0 = *(const bf16x8*)&Kp[(size_t)krc * DH + quad * 8];
      bf16x8 kf1 = *(const bf16x8*)&Kp[(size_t)krc * DH + 32 + quad * 8];
      s1 = MFMA_16x16x32_BF16(qf0, kf0, s1);
      s1 = MFMA_16x16x32_BF16(qf1, kf1, s1);
    }
    const int k0i = kc + col, k1i = kc + 16 + col;
    float tm[4];
#pragma unroll
    for (int r = 0; r < 4; ++r) {
      int q = q0 + quad * 4 + r;
      bool v0 = (k0i >= 0) & (k0i <= q) & (k0i > q - 256);
      bool v1 = (k1i >= 0) & (k1i <= q) & (k1i > q - 256);
      float a0 = v0 ? s0[r] * 0.125f : -INFINITY;
      float a1 = v1 ? s1[r] * 0.125f : -INFINITY;
      s0[r] = a0; s1[r] = a1;
      tm[r] = fmaxf(a0, a1);
    }
#pragma unroll
    for (int r = 0; r < 4; ++r) {
      tm[r] = fmaxf(tm[r], __shfl_xor(tm[r], 1));
      tm[r] = fmaxf(tm[r], __shfl_xor(tm[r], 2));
      tm[r] = fmaxf(tm[r], __shfl_xor(tm[r], 4));
      tm[r] = fmaxf(tm[r], __shfl_xor(tm[r], 8));
    }
    float alpha[4], rs[4];
#pragma unroll
    for (int r = 0; r < 4; ++r) {
      float mold = mrow[r];
      float mn = fmaxf(mold, tm[r]);
      mrow[r] = mn;
      alpha[r] = (mold == -INFINITY) ? 0.0f : __expf(mold - mn);
      float msub = fmaxf(mn, -3.0e38f);   // avoid (-inf)-(-inf) when all-masked
      float p0 = __expf(s0[r] - msub);
      float p1 = __expf(s1[r] - msub);
      s0[r] = p0; s1[r] = p1;
      rs[r] = p0 + p1;
    }
#pragma unroll
    for (int r = 0; r < 4; ++r) {
      rs[r] += __shfl_xor(rs[r], 1);
      rs[r] += __shfl_xor(rs[r], 2);
      rs[r] += __shfl_xor(rs[r], 4);
      rs[r] += __shfl_xor(rs[r], 8);
      lrow[r] = lrow[r] * alpha[r] + rs[r];
    }
    // P (16x32) C-layout -> LDS -> A-frag layout
    uint16_t* pl = plds[w];
#pragma unroll
    for (int r = 0; r < 4; ++r) {
      int row = quad * 4 + r;
      *(bf16*)&pl[row * 40 + col] = (bf16)s0[r];
      *(bf16*)&pl[row * 40 + 16 + col] = (bf16)s1[r];
    }
    __syncthreads();
    bf16x8 pf = *(const bf16x8*)&pl[col * 40 + quad * 8];
#pragma unroll
    for (int nj = 0; nj < 4; ++nj)
#pragma unroll
      for (int r = 0; r < 4; ++r) o[nj][r] *= alpha[r];
    int ko = imin(imax(kc + quad * 8, 0), LSEQ - 8);
#pragma unroll
    for (int nj = 0; nj < 4; ++nj) {
      bf16x8 vf = *(const bf16x8*)&Vp[(size_t)(nj * 16 + col) * LSEQ + ko];
      o[nj] = MFMA_16x16x32_BF16(pf, vf, o[nj]);
    }
    __syncthreads();
  }
#pragma unroll
  for (int nj = 0; nj < 4; ++nj) {
#pragma unroll
    for (int r = 0; r < 4; ++r) {
      int q = q0 + quad * 4 + r;
      int d = nj * 16 + col;
      out[((size_t)b * LSEQ + q) * DMODEL + h * DH + d] = o[nj][r] / lrow[r];
    }
  }
}

// ============================================================
// launch
// ============================================================
extern "C" void kernel_launch(void* const* d_in, const int* in_sizes, int n_in,
                              void* d_out, int out_size, void* d_ws, size_t ws_size,
                              hipStream_t stream) {
  const float* hidden = (const float*)d_in[0];
  const float* Wq = (const float*)d_in[1];
  const float* bq = (const float*)d_in[2];
  const float* Wk = (const float*)d_in[3];
  const float* bk = (const float*)d_in[4];
  const float* Wv = (const float*)d_in[5];
  const float* bv = (const float*)d_in[6];
  float* out = (float*)d_out;

  // workspace layout (bytes): needs 38 MB
  char* ws = (char*)d_ws;
  uint16_t* hb  = (uint16_t*)(ws);                       // 8 MB  bf16 hidden
  uint16_t* Wt  = (uint16_t*)(ws + ((size_t)8  << 20));  // 6 MB  bf16 W^T x3
  uint16_t* qb  = (uint16_t*)(ws + ((size_t)14 << 20));  // 8 MB  q [B,H,L,dh]
  uint16_t* kb  = (uint16_t*)(ws + ((size_t)22 << 20));  // 8 MB  k [B,H,L,dh]
  uint16_t* vtb = (uint16_t*)(ws + ((size_t)30 << 20));  // 8 MB  v^T [B,H,dh,L]

  pack_hidden<<<4096, 256, 0, stream>>>((const float4*)hidden, hb);
  pack_w<<<dim3(32, 32, 3), dim3(32, 8), 0, stream>>>(Wq, Wk, Wv, Wt);
  qkv_gemm<<<dim3(8, 32, 3), 256, 0, stream>>>(hb, Wt, bq, bk, bv, qb, kb, vtb);
  attn<<<1024, 256, 0, stream>>>(qb, kb, vtb, out);
}

// Round 2
// 160.164 us; speedup vs baseline: 1.0060x; 1.0060x over previous
//
#include <hip/hip_runtime.h>
#include <hip/hip_bf16.h>
#include <stdint.h>
#include <math.h>

// ---------- types ----------
typedef __bf16 bf16;
typedef bf16  bf16x4  __attribute__((ext_vector_type(4)));
typedef bf16  bf16x8  __attribute__((ext_vector_type(8)));
typedef float floatx4 __attribute__((ext_vector_type(4)));

#define MFMA_16x16x32_BF16(a, b, c) \
  __builtin_amdgcn_mfma_f32_16x16x32_bf16((a), (b), (c), 0, 0, 0)

__device__ __forceinline__ int imin(int a, int b) { return a < b ? a : b; }
__device__ __forceinline__ int imax(int a, int b) { return a > b ? a : b; }

// async global->LDS, 16B per lane. LDS dest is wave-uniform base + lane*16.
__device__ __forceinline__ void load_lds16(const void* g, void* l) {
  __builtin_amdgcn_global_load_lds(
      (const __attribute__((address_space(1))) unsigned int*)g,
      (__attribute__((address_space(3))) unsigned int*)l, 16, 0, 0);
}

// ---------- constants ----------
// B=2, L=2048, D=1024, H=16, dh=64, WINDOW=256
#define LSEQ 2048
#define DMODEL 1024
#define NH 16
#define DH 64

// ============================================================
// 1) hidden fp32 -> bf16 (same layout, [4096,1024])
// ============================================================
__global__ void pack_hidden(const float4* __restrict__ x, uint16_t* __restrict__ y) {
  int i = blockIdx.x * 256 + threadIdx.x;   // grid covers exactly 4096*1024/4
  float4 f = x[i];
  bf16x4 v;
  v[0] = (bf16)f.x; v[1] = (bf16)f.y; v[2] = (bf16)f.z; v[3] = (bf16)f.w;
  *(bf16x4*)&y[(size_t)i * 4] = v;          // 8B store
}

// ============================================================
// 2) W [k][n] fp32 -> Wt [n][k] bf16, 32x32 LDS tile transpose, z = q/k/v
// ============================================================
__global__ void pack_w(const float* __restrict__ Wq, const float* __restrict__ Wk,
                       const float* __restrict__ Wv, uint16_t* __restrict__ Wt) {
  __shared__ float tile[32][33];
  const int z = blockIdx.z;
  const float* W = (z == 0) ? Wq : (z == 1) ? Wk : Wv;
  const int k0 = blockIdx.y * 32, n0 = blockIdx.x * 32;
  const int tx = threadIdx.x, ty = threadIdx.y;  // block (32,8)
#pragma unroll
  for (int i = 0; i < 4; ++i)
    tile[ty + i * 8][tx] = W[(size_t)(k0 + ty + i * 8) * DMODEL + n0 + tx];
  __syncthreads();
  uint16_t* out = Wt + (size_t)z * DMODEL * DMODEL;
#pragma unroll
  for (int i = 0; i < 4; ++i)
    *(bf16*)&out[(size_t)(n0 + ty + i * 8) * DMODEL + k0 + tx] =
        (bf16)tile[tx][ty + i * 8];
}

// ============================================================
// 3) QKV GEMM, BK=64: C[m][n] = A[m][:] . W[:][n] + bias[n]
//    A: hidden bf16 [4096,1024] (k-innermost), Bt: Wt [n][k] (k-innermost)
//    128x128 tile, BK=64, 4 waves (2x2 of 64x64), 16x16x32 MFMA.
//    z=0 -> q [B,H,L,dh]; z=1 -> k same; z=2 -> v TRANSPOSED [B,H,dh,L].
// ============================================================
__global__ __launch_bounds__(256, 2) void qkv_gemm(
    const uint16_t* __restrict__ A, const uint16_t* __restrict__ Wt,
    const float* __restrict__ bq, const float* __restrict__ bk,
    const float* __restrict__ bv,
    uint16_t* __restrict__ outq, uint16_t* __restrict__ outk,
    uint16_t* __restrict__ outvt) {
  __shared__ __attribute__((aligned(16))) uint16_t lds[16384];  // A:8192, B:8192
  const int z = blockIdx.z;
  const int m0 = blockIdx.y * 128;
  const int n0 = blockIdx.x * 128;
  const uint16_t* Bt = Wt + (size_t)z * DMODEL * DMODEL;
  const float* bias = (z == 0) ? bq : (z == 1) ? bk : bv;

  const int t = threadIdx.x;
  const int lane = t & 63;
  const int wave = t >> 6;
  const int wm = (wave >> 1) * 64;
  const int wn = (wave & 1) * 64;
  const int col = lane & 15;
  const int quad = lane >> 4;

  floatx4 acc[4][4] = {};

  for (int kk = 0; kk < 16; ++kk) {
    const int k0 = kk * 64;
    // stage A-tile (128x64) + B-tile (128x64): 2048 chunks of 16B, 8/thread.
    // XOR swizzle the 8 16B-chunks of each row (on the GLOBAL side) so that
    // fragment b128 reads spread across banks.
#pragma unroll
    for (int c = 0; c < 8; ++c) {
      int chunk = t + c * 256;
      int cc = chunk & 1023;
      int row = cc >> 3;
      int col16 = (cc & 7) ^ (row & 7);
      const uint16_t* g = (chunk < 1024)
          ? A  + (size_t)(m0 + row) * DMODEL + k0 + col16 * 8
          : Bt + (size_t)(n0 + row) * DMODEL + k0 + col16 * 8;
      load_lds16(g, &lds[chunk * 8]);
    }
    __syncthreads();

#pragma unroll
    for (int s = 0; s < 2; ++s) {
      bf16x8 afrag[4], bfrag[4];
#pragma unroll
      for (int mi = 0; mi < 4; ++mi) {
        int r = wm + mi * 16 + col;
        afrag[mi] = *(const bf16x8*)&lds[r * 64 + (((s * 4 + quad) ^ (r & 7)) * 8)];
      }
#pragma unroll
      for (int nj = 0; nj < 4; ++nj) {
        int r = wn + nj * 16 + col;
        bfrag[nj] = *(const bf16x8*)&lds[8192 + r * 64 + (((s * 4 + quad) ^ (r & 7)) * 8)];
      }
#pragma unroll
      for (int mi = 0; mi < 4; ++mi)
#pragma unroll
        for (int nj = 0; nj < 4; ++nj)
          acc[mi][nj] = MFMA_16x16x32_BF16(afrag[mi], bfrag[nj], acc[mi][nj]);
    }
    __syncthreads();
  }

  // epilogue: C/D layout col=lane&15, row=quad*4+reg
#pragma unroll
  for (int nj = 0; nj < 4; ++nj) {
    int gn = n0 + wn + nj * 16 + col;
    float bb = bias[gn];
    int h = gn >> 6, d = gn & 63;
#pragma unroll
    for (int mi = 0; mi < 4; ++mi) {
#pragma unroll
      for (int r = 0; r < 4; ++r) {
        int gm = m0 + wm + mi * 16 + quad * 4 + r;
        int b = gm >> 11, l = gm & 2047;
        bf16 hv = (bf16)(acc[mi][nj][r] + bb);
        if (z == 0)
          *(bf16*)&outq[(((size_t)b * NH + h) * LSEQ + l) * DH + d] = hv;
        else if (z == 1)
          *(bf16*)&outk[(((size_t)b * NH + h) * LSEQ + l) * DH + d] = hv;
        else
          *(bf16*)&outvt[(((size_t)b * NH + h) * DH + d) * LSEQ + l] = hv;
      }
    }
  }
}

// ============================================================
// 4) windowed attention, split-window flash.
//    2 waves per 16-query tile: half0 = keys [q0-256, q0-96) (5 chunks),
//    half1 = keys [q0-96, q0+32) (4 chunks, causal mask) + merge + store.
//    No per-chunk barriers (P-LDS is wave-private); one block barrier at merge.
// ============================================================
__global__ __launch_bounds__(256, 4) void attn(
    const uint16_t* __restrict__ Q, const uint16_t* __restrict__ K,
    const uint16_t* __restrict__ Vt, float* __restrict__ out) {
  __shared__ __attribute__((aligned(16))) uint16_t plds[4][16 * 40];  // per-wave P
  __shared__ float oA[2][16][68];     // pair-merge: half0's o (padded)
  __shared__ float mlA[2][2][16];     // pair-merge: half0's m,l per row

  const int t = threadIdx.x;
  const int lane = t & 63;
  const int w = t >> 6;
  const int pair = w >> 1;
  const int half = w & 1;
  const int task = blockIdx.x * 2 + pair;  // 0..4095 q-tiles
  const int bh = task >> 7;                // 0..31
  const int q0 = (task & 127) * 16;
  const int b = bh >> 4, h = bh & 15;
  const uint16_t* Qp = Q + (size_t)bh * LSEQ * DH;
  const uint16_t* Kp = K + (size_t)bh * LSEQ * DH;
  const uint16_t* Vp = Vt + (size_t)bh * DH * LSEQ;
  const int col = lane & 15, quad = lane >> 4;

  // Q A-frags: lane holds Q[q0+col][quad*8+j], two 32-wide k chunks
  bf16x8 qf0 = *(const bf16x8*)&Qp[(size_t)(q0 + col) * DH + quad * 8];
  bf16x8 qf1 = *(const bf16x8*)&Qp[(size_t)(q0 + col) * DH + 32 + quad * 8];

  const int kb = half ? (q0 - 96) : (q0 - 256);
  const int nc = half ? 4 : 5;

  floatx4 o[4] = {};        // 16q x 64d accumulator (C layout)
  float mrow[4], lrow[4];
#pragma unroll
  for (int r = 0; r < 4; ++r) { mrow[r] = -INFINITY; lrow[r] = 0.0f; }

  // prefetch chunk-0 K frags
  bf16x8 kf0a, kf0b, kf1a, kf1b;
  {
    int krc0 = imin(imax(kb + col, 0), LSEQ - 1);
    int krc1 = imin(imax(kb + 16 + col, 0), LSEQ - 1);
    kf0a = *(const bf16x8*)&Kp[(size_t)krc0 * DH + quad * 8];
    kf0b = *(const bf16x8*)&Kp[(size_t)krc0 * DH + 32 + quad * 8];
    kf1a = *(const bf16x8*)&Kp[(size_t)krc1 * DH + quad * 8];
    kf1b = *(const bf16x8*)&Kp[(size_t)krc1 * DH + 32 + quad * 8];
  }

  for (int c = 0; c < nc; ++c) {
    const int kc = kb + c * 32;
    floatx4 s0 = {0.f, 0.f, 0.f, 0.f}, s1 = {0.f, 0.f, 0.f, 0.f};
    s0 = MFMA_16x16x32_BF16(qf0, kf0a, s0);
    s0 = MFMA_16x16x32_BF16(qf1, kf0b, s0);
    s1 = MFMA_16x16x32_BF16(qf0, kf1a, s1);
    s1 = MFMA_16x16x32_BF16(qf1, kf1b, s1);

    // prefetch next chunk's K frags (overlaps softmax below)
    if (c + 1 < nc) {
      int kn = kb + (c + 1) * 32;
      int krc0 = imin(imax(kn + col, 0), LSEQ - 1);
      int krc1 = imin(imax(kn + 16 + col, 0), LSEQ - 1);
      kf0a = *(const bf16x8*)&Kp[(size_t)krc0 * DH + quad * 8];
      kf0b = *(const bf16x8*)&Kp[(size_t)krc0 * DH + 32 + quad * 8];
      kf1a = *(const bf16x8*)&Kp[(size_t)krc1 * DH + quad * 8];
      kf1b = *(const bf16x8*)&Kp[(size_t)krc1 * DH + 32 + quad * 8];
    }
    // issue V loads for this chunk early (used after softmax)
    bf16x8 vf[4];
    int ko = imin(imax(kc + quad * 8, 0), LSEQ - 8);
#pragma unroll
    for (int nj = 0; nj < 4; ++nj)
      vf[nj] = *(const bf16x8*)&Vp[(size_t)(nj * 16 + col) * LSEQ + ko];

    const int k0i = kc + col, k1i = kc + 16 + col;
    float tm[4];
#pragma unroll
    for (int r = 0; r < 4; ++r) {
      int q = q0 + quad * 4 + r;
      bool v0, v1;
      if (half) {  // upper half: k > q-256 holds by construction
        v0 = (k0i >= 0) & (k0i <= q);
        v1 = (k1i >= 0) & (k1i <= q);
      } else {     // lower half: k <= q holds by construction
        v0 = (k0i >= 0) & (k0i > q - 256);
        v1 = (k1i >= 0) & (k1i > q - 256);
      }
      float a0 = v0 ? s0[r] * 0.125f : -INFINITY;
      float a1 = v1 ? s1[r] * 0.125f : -INFINITY;
      s0[r] = a0; s1[r] = a1;
      tm[r] = fmaxf(a0, a1);
    }
#pragma unroll
    for (int r = 0; r < 4; ++r) {
      tm[r] = fmaxf(tm[r], __shfl_xor(tm[r], 1));
      tm[r] = fmaxf(tm[r], __shfl_xor(tm[r], 2));
      tm[r] = fmaxf(tm[r], __shfl_xor(tm[r], 4));
      tm[r] = fmaxf(tm[r], __shfl_xor(tm[r], 8));
    }
    float alpha[4], rs[4];
#pragma unroll
    for (int r = 0; r < 4; ++r) {
      float mold = mrow[r];
      float mn = fmaxf(mold, tm[r]);
      mrow[r] = mn;
      alpha[r] = (mold == -INFINITY) ? 0.0f : __expf(mold - mn);
      float msub = fmaxf(mn, -3.0e38f);   // avoid (-inf)-(-inf) when all-masked
      float p0 = __expf(s0[r] - msub);
      float p1 = __expf(s1[r] - msub);
      s0[r] = p0; s1[r] = p1;
      rs[r] = p0 + p1;
    }
#pragma unroll
    for (int r = 0; r < 4; ++r) {
      rs[r] += __shfl_xor(rs[r], 1);
      rs[r] += __shfl_xor(rs[r], 2);
      rs[r] += __shfl_xor(rs[r], 4);
      rs[r] += __shfl_xor(rs[r], 8);
      lrow[r] = lrow[r] * alpha[r] + rs[r];
    }
    // P (16x32) C-layout -> wave-private LDS -> A-frag layout (no block barrier)
    uint16_t* pl = plds[w];
#pragma unroll
    for (int r = 0; r < 4; ++r) {
      int row = quad * 4 + r;
      *(bf16*)&pl[row * 40 + col] = (bf16)s0[r];
      *(bf16*)&pl[row * 40 + 16 + col] = (bf16)s1[r];
    }
    bf16x8 pf = *(const bf16x8*)&pl[col * 40 + quad * 8];
#pragma unroll
    for (int nj = 0; nj < 4; ++nj)
#pragma unroll
      for (int r = 0; r < 4; ++r) o[nj][r] *= alpha[r];
#pragma unroll
    for (int nj = 0; nj < 4; ++nj)
      o[nj] = MFMA_16x16x32_BF16(pf, vf[nj], o[nj]);
  }

  // ---- merge the two halves of each pair ----
  if (half == 0) {
#pragma unroll
    for (int nj = 0; nj < 4; ++nj)
#pragma unroll
      for (int r = 0; r < 4; ++r)
        oA[pair][quad * 4 + r][nj * 16 + col] = o[nj][r];
    if (col == 0) {
#pragma unroll
      for (int r = 0; r < 4; ++r) {
        mlA[pair][0][quad * 4 + r] = mrow[r];
        mlA[pair][1][quad * 4 + r] = lrow[r];
      }
    }
  }
  __syncthreads();
  if (half == 1) {
    float aA[4], aB[4], rinv[4];
#pragma unroll
    for (int r = 0; r < 4; ++r) {
      int row = quad * 4 + r;
      float mAv = mlA[pair][0][row];
      float lAv = mlA[pair][1][row];
      float M = fmaxf(mrow[r], mAv);        // mrow finite (k=q always valid)
      aB[r] = __expf(mrow[r] - M);
      aA[r] = (mAv == -INFINITY) ? 0.0f : __expf(mAv - M);
      float L = lrow[r] * aB[r] + lAv * aA[r];
      rinv[r] = 1.0f / L;
    }
#pragma unroll
    for (int nj = 0; nj < 4; ++nj) {
#pragma unroll
      for (int r = 0; r < 4; ++r) {
        int row = quad * 4 + r;
        int q = q0 + row;
        int d = nj * 16 + col;
        float val = (o[nj][r] * aB[r] + oA[pair][row][d] * aA[r]) * rinv[r];
        out[((size_t)b * LSEQ + q) * DMODEL + h * DH + d] = val;
      }
    }
  }
}

// ============================================================
// launch
// ============================================================
extern "C" void kernel_launch(void* const* d_in, const int* in_sizes, int n_in,
                              void* d_out, int out_size, void* d_ws, size_t ws_size,
                              hipStream_t stream) {
  const float* hidden = (const float*)d_in[0];
  const float* Wq = (const float*)d_in[1];
  const float* bq = (const float*)d_in[2];
  const float* Wk = (const float*)d_in[3];
  const float* bk = (const float*)d_in[4];
  const float* Wv = (const float*)d_in[5];
  const float* bv = (const float*)d_in[6];
  float* out = (float*)d_out;

  // workspace layout (bytes): needs 38 MB
  char* ws = (char*)d_ws;
  uint16_t* hb  = (uint16_t*)(ws);                       // 8 MB  bf16 hidden
  uint16_t* Wt  = (uint16_t*)(ws + ((size_t)8  << 20));  // 6 MB  bf16 W^T x3
  uint16_t* qb  = (uint16_t*)(ws + ((size_t)14 << 20));  // 8 MB  q [B,H,L,dh]
  uint16_t* kb  = (uint16_t*)(ws + ((size_t)22 << 20));  // 8 MB  k [B,H,L,dh]
  uint16_t* vtb = (uint16_t*)(ws + ((size_t)30 << 20));  // 8 MB  v^T [B,H,dh,L]

  pack_hidden<<<4096, 256, 0, stream>>>((const float4*)hidden, hb);
  pack_w<<<dim3(32, 32, 3), dim3(32, 8), 0, stream>>>(Wq, Wk, Wv, Wt);
  qkv_gemm<<<dim3(8, 32, 3), 256, 0, stream>>>(hb, Wt, bq, bk, bv, qb, kb, vtb);
  attn<<<2048, 256, 0, stream>>>(qb, kb, vtb, out);
}

// Round 3
// 155.494 us; speedup vs baseline: 1.0362x; 1.0300x over previous
//
#include <hip/hip_runtime.h>
#include <hip/hip_bf16.h>
#include <stdint.h>
#include <math.h>

// ---------- types ----------
typedef __bf16 bf16;
typedef bf16  bf16x4  __attribute__((ext_vector_type(4)));
typedef bf16  bf16x8  __attribute__((ext_vector_type(8)));
typedef float floatx4 __attribute__((ext_vector_type(4)));

#define MFMA_16x16x32_BF16(a, b, c) \
  __builtin_amdgcn_mfma_f32_16x16x32_bf16((a), (b), (c), 0, 0, 0)

__device__ __forceinline__ int imin(int a, int b) { return a < b ? a : b; }
__device__ __forceinline__ int imax(int a, int b) { return a > b ? a : b; }

// async global->LDS, 16B per lane. LDS dest is wave-uniform base + lane*16.
__device__ __forceinline__ void load_lds16(const void* g, void* l) {
  __builtin_amdgcn_global_load_lds(
      (const __attribute__((address_space(1))) unsigned int*)g,
      (__attribute__((address_space(3))) unsigned int*)l, 16, 0, 0);
}

// ---------- constants ----------
// B=2, L=2048, D=1024, H=16, dh=64, WINDOW=256
#define LSEQ 2048
#define DMODEL 1024
#define NH 16
#define DH 64

// ============================================================
// 1) hidden fp32 -> bf16 (same layout, [4096,1024])
// ============================================================
__global__ void pack_hidden(const float4* __restrict__ x, uint16_t* __restrict__ y) {
  int i = blockIdx.x * 256 + threadIdx.x;   // grid covers exactly 4096*1024/4
  float4 f = x[i];
  bf16x4 v;
  v[0] = (bf16)f.x; v[1] = (bf16)f.y; v[2] = (bf16)f.z; v[3] = (bf16)f.w;
  *(bf16x4*)&y[(size_t)i * 4] = v;          // 8B store
}

// ============================================================
// 2) W [k][n] fp32 -> Wt [n][k] bf16, 32x32 LDS tile transpose, z = q/k/v
// ============================================================
__global__ void pack_w(const float* __restrict__ Wq, const float* __restrict__ Wk,
                       const float* __restrict__ Wv, uint16_t* __restrict__ Wt) {
  __shared__ float tile[32][33];
  const int z = blockIdx.z;
  const float* W = (z == 0) ? Wq : (z == 1) ? Wk : Wv;
  const int k0 = blockIdx.y * 32, n0 = blockIdx.x * 32;
  const int tx = threadIdx.x, ty = threadIdx.y;  // block (32,8)
#pragma unroll
  for (int i = 0; i < 4; ++i)
    tile[ty + i * 8][tx] = W[(size_t)(k0 + ty + i * 8) * DMODEL + n0 + tx];
  __syncthreads();
  uint16_t* out = Wt + (size_t)z * DMODEL * DMODEL;
#pragma unroll
  for (int i = 0; i < 4; ++i)
    *(bf16*)&out[(size_t)(n0 + ty + i * 8) * DMODEL + k0 + tx] =
        (bf16)tile[tx][ty + i * 8];
}

// ============================================================
// 3) QKV GEMM, BK=64: C[m][n] = A[m][:] . W[:][n] + bias[n]
//    z=0 -> q*0.125 [B,H,L,dh]; z=1 -> k; z=2 -> v TRANSPOSED [B,H,dh,L].
// ============================================================
__global__ __launch_bounds__(256, 2) void qkv_gemm(
    const uint16_t* __restrict__ A, const uint16_t* __restrict__ Wt,
    const float* __restrict__ bq, const float* __restrict__ bk,
    const float* __restrict__ bv,
    uint16_t* __restrict__ outq, uint16_t* __restrict__ outk,
    uint16_t* __restrict__ outvt) {
  __shared__ __attribute__((aligned(16))) uint16_t lds[16384];  // A:8192, B:8192
  const int z = blockIdx.z;
  const int m0 = blockIdx.y * 128;
  const int n0 = blockIdx.x * 128;
  const uint16_t* Bt = Wt + (size_t)z * DMODEL * DMODEL;
  const float* bias = (z == 0) ? bq : (z == 1) ? bk : bv;

  const int t = threadIdx.x;
  const int lane = t & 63;
  const int wave = t >> 6;
  const int wm = (wave >> 1) * 64;
  const int wn = (wave & 1) * 64;
  const int col = lane & 15;
  const int quad = lane >> 4;

  floatx4 acc[4][4] = {};

  for (int kk = 0; kk < 16; ++kk) {
    const int k0 = kk * 64;
#pragma unroll
    for (int c = 0; c < 8; ++c) {
      int chunk = t + c * 256;
      int cc = chunk & 1023;
      int row = cc >> 3;
      int col16 = (cc & 7) ^ (row & 7);
      const uint16_t* g = (chunk < 1024)
          ? A  + (size_t)(m0 + row) * DMODEL + k0 + col16 * 8
          : Bt + (size_t)(n0 + row) * DMODEL + k0 + col16 * 8;
      load_lds16(g, &lds[chunk * 8]);
    }
    __syncthreads();

#pragma unroll
    for (int s = 0; s < 2; ++s) {
      bf16x8 afrag[4], bfrag[4];
#pragma unroll
      for (int mi = 0; mi < 4; ++mi) {
        int r = wm + mi * 16 + col;
        afrag[mi] = *(const bf16x8*)&lds[r * 64 + (((s * 4 + quad) ^ (r & 7)) * 8)];
      }
#pragma unroll
      for (int nj = 0; nj < 4; ++nj) {
        int r = wn + nj * 16 + col;
        bfrag[nj] = *(const bf16x8*)&lds[8192 + r * 64 + (((s * 4 + quad) ^ (r & 7)) * 8)];
      }
#pragma unroll
      for (int mi = 0; mi < 4; ++mi)
#pragma unroll
        for (int nj = 0; nj < 4; ++nj)
          acc[mi][nj] = MFMA_16x16x32_BF16(afrag[mi], bfrag[nj], acc[mi][nj]);
    }
    __syncthreads();
  }

  // epilogue: C/D layout col=lane&15, row=quad*4+reg
  const float scale = (z == 0) ? 0.125f : 1.0f;  // fold 1/sqrt(dh) into q (exact)
#pragma unroll
  for (int nj = 0; nj < 4; ++nj) {
    int gn = n0 + wn + nj * 16 + col;
    float bb = bias[gn];
    int h = gn >> 6, d = gn & 63;
#pragma unroll
    for (int mi = 0; mi < 4; ++mi) {
#pragma unroll
      for (int r = 0; r < 4; ++r) {
        int gm = m0 + wm + mi * 16 + quad * 4 + r;
        int b = gm >> 11, l = gm & 2047;
        bf16 hv = (bf16)((acc[mi][nj][r] + bb) * scale);
        if (z == 0)
          *(bf16*)&outq[(((size_t)b * NH + h) * LSEQ + l) * DH + d] = hv;
        else if (z == 1)
          *(bf16*)&outk[(((size_t)b * NH + h) * LSEQ + l) * DH + d] = hv;
        else
          *(bf16*)&outvt[(((size_t)b * NH + h) * DH + d) * LSEQ + l] = hv;
      }
    }
  }
}

// ============================================================
// 4) windowed attention, split-window flash, XCD-pinned heads.
//    blockIdx%8 = XCD; each (b,h) maps to exactly one XCD so its K/V
//    (512 KB) stays in that XCD's L2 (4 MB holds 4 heads).
//    2 waves per 16-query tile: half0 = keys [q0-256,q0-96), half1 =
//    [q0-96,q0+32) + merge + store. Mask VALU only on boundary chunks.
// ============================================================
__global__ __launch_bounds__(256, 4) void attn(
    const uint16_t* __restrict__ Q, const uint16_t* __restrict__ K,
    const uint16_t* __restrict__ Vt, float* __restrict__ out) {
  __shared__ __attribute__((aligned(16))) uint16_t plds[4][16 * 40];  // per-wave P
  __shared__ float oA[2][16][68];     // pair-merge: half0's o (padded)
  __shared__ float mlA[2][2][16];     // pair-merge: half0's m,l per row

  const int t = threadIdx.x;
  const int lane = t & 63;
  const int w = t >> 6;
  const int pair = w >> 1;
  const int half = w & 1;
  // XCD-pinning swizzle: xcd = blockIdx.x & 7 (HW round-robin), 256 slots/XCD,
  // 64 slots per head -> 4 heads per XCD.
  const int xcd = blockIdx.x & 7;
  const int slot = blockIdx.x >> 3;
  const int bh = xcd * 4 + (slot >> 6);
  const int tile = (slot & 63) * 2 + pair;   // 0..127
  const int q0 = tile * 16;
  const int b = bh >> 4, h = bh & 15;
  const uint16_t* Qp = Q + (size_t)bh * LSEQ * DH;
  const uint16_t* Kp = K + (size_t)bh * LSEQ * DH;
  const uint16_t* Vp = Vt + (size_t)bh * DH * LSEQ;
  const int col = lane & 15, quad = lane >> 4;

  // Q A-frags (pre-scaled by 0.125 in qkv_gemm)
  bf16x8 qf0 = *(const bf16x8*)&Qp[(size_t)(q0 + col) * DH + quad * 8];
  bf16x8 qf1 = *(const bf16x8*)&Qp[(size_t)(q0 + col) * DH + 32 + quad * 8];

  const int kb = half ? (q0 - 96) : (q0 - 256);
  const int nc = half ? 4 : 5;

  floatx4 o[4] = {};        // 16q x 64d accumulator (C layout)
  float mrow[4], lrow[4];
#pragma unroll
  for (int r = 0; r < 4; ++r) { mrow[r] = -INFINITY; lrow[r] = 0.0f; }

  // prefetch chunk-0 K frags
  bf16x8 kf0a, kf0b, kf1a, kf1b;
  {
    int krc0 = imin(imax(kb + col, 0), LSEQ - 1);
    int krc1 = imin(imax(kb + 16 + col, 0), LSEQ - 1);
    kf0a = *(const bf16x8*)&Kp[(size_t)krc0 * DH + quad * 8];
    kf0b = *(const bf16x8*)&Kp[(size_t)krc0 * DH + 32 + quad * 8];
    kf1a = *(const bf16x8*)&Kp[(size_t)krc1 * DH + quad * 8];
    kf1b = *(const bf16x8*)&Kp[(size_t)krc1 * DH + 32 + quad * 8];
  }

  for (int c = 0; c < nc; ++c) {
    const int kc = kb + c * 32;
    floatx4 s0 = {0.f, 0.f, 0.f, 0.f}, s1 = {0.f, 0.f, 0.f, 0.f};
    s0 = MFMA_16x16x32_BF16(qf0, kf0a, s0);
    s0 = MFMA_16x16x32_BF16(qf1, kf0b, s0);
    s1 = MFMA_16x16x32_BF16(qf0, kf1a, s1);
    s1 = MFMA_16x16x32_BF16(qf1, kf1b, s1);

    // prefetch next chunk's K frags (overlaps softmax below)
    if (c + 1 < nc) {
      int kn = kb + (c + 1) * 32;
      int krc0 = imin(imax(kn + col, 0), LSEQ - 1);
      int krc1 = imin(imax(kn + 16 + col, 0), LSEQ - 1);
      kf0a = *(const bf16x8*)&Kp[(size_t)krc0 * DH + quad * 8];
      kf0b = *(const bf16x8*)&Kp[(size_t)krc0 * DH + 32 + quad * 8];
      kf1a = *(const bf16x8*)&Kp[(size_t)krc1 * DH + quad * 8];
      kf1b = *(const bf16x8*)&Kp[(size_t)krc1 * DH + 32 + quad * 8];
    }
    // issue V loads for this chunk early (used after softmax)
    bf16x8 vf[4];
    int ko = imin(imax(kc + quad * 8, 0), LSEQ - 8);
#pragma unroll
    for (int nj = 0; nj < 4; ++nj)
      vf[nj] = *(const bf16x8*)&Vp[(size_t)(nj * 16 + col) * LSEQ + ko];

    // boundary chunks: half0 c==0 (lower diagonal), kc<0 (seq start),
    // half1 last chunk (causal diagonal). Interior: all 512 scores valid.
    const bool needm = (kc < 0) | (!half & (c == 0)) | (half & (c == nc - 1));
    float tm[4];
    if (needm) {
      const int k0i = kc + col, k1i = kc + 16 + col;
#pragma unroll
      for (int r = 0; r < 4; ++r) {
        int q = q0 + quad * 4 + r;
        bool v0, v1;
        if (half) { v0 = (k0i >= 0) & (k0i <= q); v1 = (k1i >= 0) & (k1i <= q); }
        else      { v0 = (k0i >= 0) & (k0i > q - 256); v1 = (k1i >= 0) & (k1i > q - 256); }
        float a0 = v0 ? s0[r] : -INFINITY;
        float a1 = v1 ? s1[r] : -INFINITY;
        s0[r] = a0; s1[r] = a1;
        tm[r] = fmaxf(a0, a1);
      }
    } else {
#pragma unroll
      for (int r = 0; r < 4; ++r) tm[r] = fmaxf(s0[r], s1[r]);
    }
#pragma unroll
    for (int r = 0; r < 4; ++r) {
      tm[r] = fmaxf(tm[r], __shfl_xor(tm[r], 1));
      tm[r] = fmaxf(tm[r], __shfl_xor(tm[r], 2));
      tm[r] = fmaxf(tm[r], __shfl_xor(tm[r], 4));
      tm[r] = fmaxf(tm[r], __shfl_xor(tm[r], 8));
    }
    float alpha[4], rs[4];
#pragma unroll
    for (int r = 0; r < 4; ++r) {
      float mold = mrow[r];
      float mn = fmaxf(mold, tm[r]);
      mrow[r] = mn;
      alpha[r] = (mold == -INFINITY) ? 0.0f : __expf(mold - mn);
      float msub = needm ? fmaxf(mn, -3.0e38f) : mn;  // all-masked guard
      float p0 = __expf(s0[r] - msub);
      float p1 = __expf(s1[r] - msub);
      s0[r] = p0; s1[r] = p1;
      rs[r] = p0 + p1;
    }
#pragma unroll
    for (int r = 0; r < 4; ++r) {
      rs[r] += __shfl_xor(rs[r], 1);
      rs[r] += __shfl_xor(rs[r], 2);
      rs[r] += __shfl_xor(rs[r], 4);
      rs[r] += __shfl_xor(rs[r], 8);
      lrow[r] = lrow[r] * alpha[r] + rs[r];
    }
    // P (16x32) C-layout -> wave-private LDS -> A-frag layout (no block barrier)
    uint16_t* pl = plds[w];
#pragma unroll
    for (int r = 0; r < 4; ++r) {
      int row = quad * 4 + r;
      *(bf16*)&pl[row * 40 + col] = (bf16)s0[r];
      *(bf16*)&pl[row * 40 + 16 + col] = (bf16)s1[r];
    }
    bf16x8 pf = *(const bf16x8*)&pl[col * 40 + quad * 8];
#pragma unroll
    for (int nj = 0; nj < 4; ++nj)
#pragma unroll
      for (int r = 0; r < 4; ++r) o[nj][r] *= alpha[r];
#pragma unroll
    for (int nj = 0; nj < 4; ++nj)
      o[nj] = MFMA_16x16x32_BF16(pf, vf[nj], o[nj]);
  }

  // ---- merge the two halves of each pair ----
  if (half == 0) {
#pragma unroll
    for (int nj = 0; nj < 4; ++nj)
#pragma unroll
      for (int r = 0; r < 4; ++r)
        oA[pair][quad * 4 + r][nj * 16 + col] = o[nj][r];
    if (col == 0) {
#pragma unroll
      for (int r = 0; r < 4; ++r) {
        mlA[pair][0][quad * 4 + r] = mrow[r];
        mlA[pair][1][quad * 4 + r] = lrow[r];
      }
    }
  }
  __syncthreads();
  if (half == 1) {
    float aA[4], aB[4], rinv[4];
#pragma unroll
    for (int r = 0; r < 4; ++r) {
      int row = quad * 4 + r;
      float mAv = mlA[pair][0][row];
      float lAv = mlA[pair][1][row];
      float M = fmaxf(mrow[r], mAv);        // mrow finite (k=q always valid)
      aB[r] = __expf(mrow[r] - M);
      aA[r] = (mAv == -INFINITY) ? 0.0f : __expf(mAv - M);
      float L = lrow[r] * aB[r] + lAv * aA[r];
      rinv[r] = 1.0f / L;
    }
#pragma unroll
    for (int nj = 0; nj < 4; ++nj) {
#pragma unroll
      for (int r = 0; r < 4; ++r) {
        int row = quad * 4 + r;
        int q = q0 + row;
        int d = nj * 16 + col;
        float val = (o[nj][r] * aB[r] + oA[pair][row][d] * aA[r]) * rinv[r];
        out[((size_t)b * LSEQ + q) * DMODEL + h * DH + d] = val;
      }
    }
  }
}

// ============================================================
// launch
// ============================================================
extern "C" void kernel_launch(void* const* d_in, const int* in_sizes, int n_in,
                              void* d_out, int out_size, void* d_ws, size_t ws_size,
                              hipStream_t stream) {
  const float* hidden = (const float*)d_in[0];
  const float* Wq = (const float*)d_in[1];
  const float* bq = (const float*)d_in[2];
  const float* Wk = (const float*)d_in[3];
  const float* bk = (const float*)d_in[4];
  const float* Wv = (const float*)d_in[5];
  const float* bv = (const float*)d_in[6];
  float* out = (float*)d_out;

  // workspace layout (bytes): needs 38 MB
  char* ws = (char*)d_ws;
  uint16_t* hb  = (uint16_t*)(ws);                       // 8 MB  bf16 hidden
  uint16_t* Wt  = (uint16_t*)(ws + ((size_t)8  << 20));  // 6 MB  bf16 W^T x3
  uint16_t* qb  = (uint16_t*)(ws + ((size_t)14 << 20));  // 8 MB  q*0.125 [B,H,L,dh]
  uint16_t* kb  = (uint16_t*)(ws + ((size_t)22 << 20));  // 8 MB  k [B,H,L,dh]
  uint16_t* vtb = (uint16_t*)(ws + ((size_t)30 << 20));  // 8 MB  v^T [B,H,dh,L]

  pack_hidden<<<4096, 256, 0, stream>>>((const float4*)hidden, hb);
  pack_w<<<dim3(32, 32, 3), dim3(32, 8), 0, stream>>>(Wq, Wk, Wv, Wt);
  qkv_gemm<<<dim3(8, 32, 3), 256, 0, stream>>>(hb, Wt, bq, bk, bv, qb, kb, vtb);
  attn<<<2048, 256, 0, stream>>>(qb, kb, vtb, out);
}